// Round 1
// baseline (13444.278 us; speedup 1.0000x reference)
//
#include <hip/hip_runtime.h>
#include <hip/hip_cooperative_groups.h>
#include <math.h>

namespace cg = cooperative_groups;

#define T_STEPS 64
#define BATCH   16
#define IN_DIM  512
#define HID     512
#define OUT_DIM 512
#define NSLOT   256
#define WORDW   64
#define RH      4
#define IFACE_N 471
#define EPS_    1e-6f

#define GRID_BLOCKS   64
#define BLOCK_THREADS 256
#define TOT_THREADS   (GRID_BLOCKS * BLOCK_THREADS)

__device__ __forceinline__ float sigmoidf_(float x) {
    return 1.f / (1.f + expf(-x));
}
__device__ __forceinline__ float oneplusf_(float x) {
    // 1 + softplus(x), stable
    return 1.f + fmaxf(x, 0.f) + log1pf(expf(-fabsf(x)));
}
__device__ __forceinline__ float wsum_(float v) {
#pragma unroll
    for (int off = 32; off > 0; off >>= 1) v += __shfl_xor(v, off, 64);
    return v;
}
__device__ __forceinline__ float blockSum_(float v, float* buf) {
    int tid = threadIdx.x;
    __syncthreads();
    buf[tid] = v;
    __syncthreads();
    for (int s = 128; s > 0; s >>= 1) {
        if (tid < s) buf[tid] += buf[tid + s];
        __syncthreads();
    }
    float r = buf[0];
    __syncthreads();
    return r;
}
__device__ __forceinline__ float blockMax_(float v, float* buf) {
    int tid = threadIdx.x;
    __syncthreads();
    buf[tid] = v;
    __syncthreads();
    for (int s = 128; s > 0; s >>= 1) {
        if (tid < s) buf[tid] = fmaxf(buf[tid], buf[tid + s]);
        __syncthreads();
    }
    float r = buf[0];
    __syncthreads();
    return r;
}

// iface column offsets
#define OFF_RK 0
#define OFF_RB 256
#define OFF_WK 260
#define OFF_WB 324
#define OFF_EV 325
#define OFF_WV 389
#define OFF_FG 453
#define OFF_AG 457
#define OFF_WG 458
#define OFF_RM 459

__global__ void __launch_bounds__(BLOCK_THREADS)
neucom_kernel(const float* __restrict__ x, const float* __restrict__ W_hid,
              const float* __restrict__ b_hid, const float* __restrict__ W_iface,
              const float* __restrict__ W_out, const float* __restrict__ W_memout,
              float* __restrict__ out, float* __restrict__ ws) {
    cg::grid_group grid = cg::this_grid();
    const int tid  = threadIdx.x;
    const int gtid = blockIdx.x * BLOCK_THREADS + tid;

    // workspace layout (floats)
    float* rv   = ws;                 // 4096  (B,R,W)
    float* hbuf = rv + 4096;          // 8192  (B,H)
    float* pre  = hbuf + 8192;        // 8192  (B,O)
    float* ifc  = pre + 8192;         // 7536 (+pad 7680) (B,471)
    float* u    = ifc + 7680;         // 4096  (B,N)
    float* pp   = u + 4096;           // 8192  two (B,N) ping-pong
    float* wwv  = pp + 8192;          // 4096  (B,N)
    float* rwv  = wwv + 4096;         // 16384 (B,R,N)
    float* rc   = rwv + 16384;        // 16384 (B,R,N)
    float* fwd  = rc + 16384;         // 16384
    float* bwd  = fwd + 16384;        // 16384
    float* M    = bwd + 16384;        // 262144 (B,N,W)
    float* L    = M + 262144;         // 1048576 (B,N,N)
    float* LT   = L + 1048576;        // 1048576 transpose

    __shared__ float smf[4288];
    __shared__ int   smi[256];

    // ---- init state (ws is poisoned 0xAA each call) ----
    for (int i = gtid; i < 4096; i += TOT_THREADS) { rv[i] = 0.f; u[i] = 0.f; wwv[i] = 0.f; }
    for (int i = gtid; i < 8192; i += TOT_THREADS) pp[i] = 0.f;
    for (int i = gtid; i < 16384; i += TOT_THREADS) rwv[i] = 0.f;
    for (int i = gtid; i < 262144; i += TOT_THREADS) M[i] = 1e-6f;
    for (int i = gtid; i < 1048576; i += TOT_THREADS) L[i] = 0.f;
    grid.sync();

    for (int t = 0; t < T_STEPS; t++) {
        float* pA = pp + (t & 1) * 4096;        // old precedence
        float* pB = pp + ((t + 1) & 1) * 4096;  // new precedence

        // ======== S1: h(t) GEMV  +  out(t-1) GEMV ========
        {
            int gt = gtid;
            if (gt < 8192) {
                int b = gt >> 9, c = gt & 511;
                const float* xr  = x + ((size_t)t * BATCH + b) * IN_DIM;
                const float* rvb = rv + b * 256;
                float acc = b_hid[c];
#pragma unroll 8
                for (int k = 0; k < 512; k++) acc = fmaf(xr[k], W_hid[k * 512 + c], acc);
#pragma unroll 8
                for (int k = 0; k < 256; k++) acc = fmaf(rvb[k], W_hid[(512 + k) * 512 + c], acc);
                hbuf[gt] = fmaxf(acc, 0.f);
            } else if (t > 0) {
                int j = gt - 8192;
                int b = j >> 9, c = j & 511;
                const float* rvb = rv + b * 256;
                float acc = pre[j];
#pragma unroll 8
                for (int k = 0; k < 256; k++) acc = fmaf(rvb[k], W_memout[k * 512 + c], acc);
                out[(size_t)(t - 1) * 8192 + j] = acc;
            }
        }
        grid.sync();

        // ======== S2: pre_out + iface GEMVs ========
        {
            int gt = gtid;
            if (gt < 8192) {
                int b = gt >> 9, c = gt & 511;
                const float* hb = hbuf + b * 512;
                float acc = 0.f;
#pragma unroll 8
                for (int k = 0; k < 512; k++) acc = fmaf(hb[k], W_out[k * 512 + c], acc);
                pre[gt] = acc;
            } else {
                int j = gt - 8192;
                if (j < BATCH * IFACE_N) {
                    int b = j / IFACE_N, c = j - b * IFACE_N;
                    const float* hb = hbuf + b * 512;
                    float acc = 0.f;
#pragma unroll 8
                    for (int k = 0; k < 512; k++) acc = fmaf(hb[k], W_iface[k * IFACE_N + c], acc);
                    ifc[b * IFACE_N + c] = acc;
                }
            }
        }
        grid.sync();

        // ======== S3 (blocks 0..15): usage, sort/alloc, write content, ww, p ========
        if (blockIdx.x < BATCH) {
            int b = blockIdx.x;
            int n = tid;
            const float* ifb = ifc + b * IFACE_N;
            float* skey  = smf;          // 256
            float* sscan = smf + 256;    // 256
            float* sa    = smf + 512;    // 256
            float* scw   = smf + 768;    // 256
            float* red   = smf + 1024;   // 256
            float* knl   = smf + 1280;   // 64

            // retention & usage
            float ret = 1.f;
#pragma unroll
            for (int r = 0; r < RH; r++) {
                float fg = sigmoidf_(ifb[OFF_FG + r]);
                ret *= (1.f - fg * rwv[b * 1024 + r * 256 + n]);
            }
            float uo = u[b * 256 + n], wo = wwv[b * 256 + n];
            float un = (uo + wo - uo * wo) * ret;
            u[b * 256 + n] = un;

            // stable bitonic argsort ascending (tie-break on index == jnp stable argsort)
            skey[n] = un;
            smi[n]  = n;
            __syncthreads();
            for (int k = 2; k <= 256; k <<= 1) {
                for (int j = k >> 1; j > 0; j >>= 1) {
                    int ixj = n ^ j;
                    if (ixj > n) {
                        float a = skey[n], c2 = skey[ixj];
                        int ia = smi[n], ic = smi[ixj];
                        bool agtb = (a > c2) || (a == c2 && ia > ic);
                        bool up = ((n & k) == 0);
                        if (agtb == up) {
                            skey[n] = c2; skey[ixj] = a;
                            smi[n] = ic;  smi[ixj] = ia;
                        }
                    }
                    __syncthreads();
                }
            }
            // inclusive product scan of sorted usage
            sscan[n] = skey[n];
            __syncthreads();
            for (int off = 1; off < 256; off <<= 1) {
                float prev = (n >= off) ? sscan[n - off] : 1.f;
                __syncthreads();
                sscan[n] *= prev;
                __syncthreads();
            }
            float cpex  = (n == 0) ? 1.f : sscan[n - 1];
            float asort = (1.f - skey[n]) * cpex;
            sa[smi[n]] = asort;  // scatter back to slot order

            // write-key normalize (wave 0)
            if (n < 64) {
                float kv = ifb[OFF_WK + n];
                float ss = wsum_(kv * kv);
                knl[n] = kv / (sqrtf(ss) + EPS_);
            }
            __syncthreads();

            // content sim over old M
            float wb = oneplusf_(ifb[OFF_WB]);
            {
                int wave = n >> 6, lane = n & 63;
                for (int rr = 0; rr < 64; rr++) {
                    int row = rr * 4 + wave;
                    float Mv = M[b * 16384 + row * 64 + lane];
                    float ss = wsum_(Mv * Mv);
                    float dt = wsum_(Mv * knl[lane]);
                    if (lane == 0) scw[row] = wb * dt / (sqrtf(ss) + EPS_);
                }
            }
            __syncthreads();
            // softmax over slots
            float v  = scw[n];
            float mx = blockMax_(v, red);
            float e  = expf(v - mx);
            float s  = blockSum_(e, red);
            float cwn = e / s;

            float ag = sigmoidf_(ifb[OFF_AG]);
            float wg = sigmoidf_(ifb[OFF_WG]);
            float wwn = wg * (ag * sa[n] + (1.f - ag) * cwn);
            wwv[b * 256 + n] = wwn;
            float wws = blockSum_(wwn, red);
            pB[b * 256 + n] = (1.f - wws) * pA[b * 256 + n] + wwn;
        }
        grid.sync();

        // ======== S4: L update (+ transpose to LT) and M update ========
        {
            for (int q = 0; q < 4; q++) {
                int tile = blockIdx.x * 4 + q;     // 256 tiles
                int b = tile >> 4;
                int rem = tile & 15;
                int ti = rem >> 2, tj = rem & 3;
                int lr = tid >> 6;   // 0..3
                int c  = tid & 63;
                __syncthreads();
#pragma unroll
                for (int rr = 0; rr < 16; rr++) {
                    int il = lr + rr * 4;
                    int ig = ti * 64 + il;
                    int jg = tj * 64 + c;
                    int idx = b * 65536 + ig * 256 + jg;
                    float lv  = L[idx];
                    float wwi = wwv[b * 256 + ig];
                    float wwj = wwv[b * 256 + jg];
                    float pj  = pA[b * 256 + jg];
                    float nv  = (1.f - wwi - wwj) * lv + wwi * pj;
                    if (ig == jg) nv = 0.f;
                    L[idx] = nv;
                    smf[il * 65 + c] = nv;
                }
                __syncthreads();
#pragma unroll
                for (int rr = 0; rr < 16; rr++) {
                    int jl = lr + rr * 4;
                    int jg = tj * 64 + jl;
                    int ig = ti * 64 + c;
                    LT[b * 65536 + jg * 256 + ig] = smf[c * 65 + jl];
                }
            }
            // M update (elementwise)
            for (int idx = gtid; idx < 262144; idx += TOT_THREADS) {
                int b = idx >> 14;
                int nn = (idx >> 6) & 255;
                int w = idx & 63;
                float wwn = wwv[b * 256 + nn];
                float ev = sigmoidf_(ifc[b * IFACE_N + OFF_EV + w]);
                float wv = ifc[b * IFACE_N + OFF_WV + w];
                M[idx] = M[idx] * (1.f - wwn * ev) + wwn * wv;
            }
        }
        grid.sync();

        // ======== S5: read content weights (blocks 0..15) + fwd/bwd (blocks 16..63) ====
        if (blockIdx.x < BATCH) {
            int b = blockIdx.x;
            const float* ifb = ifc + b * IFACE_N;
            float* red  = smf + 1024;  // 256
            float* kn4  = smf + 1280;  // 256
            float* sim4 = smf + 1536;  // 1024
            int r = tid >> 6, lane = tid & 63;
            {
                float kv = ifb[OFF_RK + r * 64 + lane];
                float ss = wsum_(kv * kv);
                kn4[r * 64 + lane] = kv / (sqrtf(ss) + EPS_);
            }
            __syncthreads();
            for (int rr = 0; rr < 64; rr++) {
                int row = rr * 4 + r;
                float Mv = M[b * 16384 + row * 64 + lane];
                float ss = wsum_(Mv * Mv);
                float d0 = wsum_(Mv * kn4[lane]);
                float d1 = wsum_(Mv * kn4[64 + lane]);
                float d2 = wsum_(Mv * kn4[128 + lane]);
                float d3 = wsum_(Mv * kn4[192 + lane]);
                if (lane == 0) {
                    float inv = 1.f / (sqrtf(ss) + EPS_);
                    sim4[0 * 256 + row] = d0 * inv;
                    sim4[1 * 256 + row] = d1 * inv;
                    sim4[2 * 256 + row] = d2 * inv;
                    sim4[3 * 256 + row] = d3 * inv;
                }
            }
            __syncthreads();
            for (int r2 = 0; r2 < RH; r2++) {
                float rb = oneplusf_(ifb[OFF_RB + r2]);
                float v  = rb * sim4[r2 * 256 + tid];
                float mx = blockMax_(v, red);
                float e  = expf(v - mx);
                float s  = blockSum_(e, red);
                rc[b * 1024 + r2 * 256 + tid] = e / s;
            }
        } else {
            int wid  = (blockIdx.x - BATCH) * 4 + (tid >> 6); // 0..191
            int lane = tid & 63;
            for (int task = wid; task < 8192; task += 192) {
                int isb = task >> 12;           // 0: fwd (L rows), 1: bwd (LT rows)
                int rn  = task & 4095;
                int b = rn >> 8, n = rn & 255;
                const float* Lr  = (isb ? LT : L) + b * 65536 + n * 256;
                const float* rwb = rwv + b * 1024;
                float a0 = 0.f, a1 = 0.f, a2 = 0.f, a3 = 0.f;
#pragma unroll
                for (int i = 0; i < 4; i++) {
                    int m = i * 64 + lane;
                    float lv = Lr[m];
                    a0 = fmaf(lv, rwb[m], a0);
                    a1 = fmaf(lv, rwb[256 + m], a1);
                    a2 = fmaf(lv, rwb[512 + m], a2);
                    a3 = fmaf(lv, rwb[768 + m], a3);
                }
                a0 = wsum_(a0); a1 = wsum_(a1); a2 = wsum_(a2); a3 = wsum_(a3);
                if (lane == 0) {
                    float* dst = (isb ? bwd : fwd) + b * 1024 + n;
                    dst[0] = a0; dst[256] = a1; dst[512] = a2; dst[768] = a3;
                }
            }
        }
        grid.sync();

        // ======== S6 (blocks 0..15): rw_new, rv_new ========
        if (blockIdx.x < BATCH) {
            int b = blockIdx.x;
            const float* ifb = ifc + b * IFACE_N;
            float* srw = smf + 1536;  // 1024
            int n = tid;
            __syncthreads();
#pragma unroll
            for (int r = 0; r < RH; r++) {
                float e0 = ifb[OFF_RM + r * 3 + 0];
                float e1 = ifb[OFF_RM + r * 3 + 1];
                float e2 = ifb[OFF_RM + r * 3 + 2];
                float mx = fmaxf(e0, fmaxf(e1, e2));
                float x0 = expf(e0 - mx), x1 = expf(e1 - mx), x2 = expf(e2 - mx);
                float inv = 1.f / (x0 + x1 + x2);
                float val = x0 * inv * bwd[b * 1024 + r * 256 + n]
                          + x1 * inv * rc[b * 1024 + r * 256 + n]
                          + x2 * inv * fwd[b * 1024 + r * 256 + n];
                srw[r * 256 + n] = val;
                rwv[b * 1024 + r * 256 + n] = val;
            }
            __syncthreads();
            {
                int r = tid >> 6, w = tid & 63;
                float acc = 0.f;
#pragma unroll 8
                for (int nn = 0; nn < 256; nn++)
                    acc = fmaf(M[b * 16384 + nn * 64 + w], srw[r * 256 + nn], acc);
                rv[b * 256 + r * 64 + w] = acc;
            }
        }
        grid.sync();
    }

    // ======== epilogue: out(T-1) ========
    {
        int gt = gtid;
        if (gt < 8192) {
            int b = gt >> 9, c = gt & 511;
            const float* rvb = rv + b * 256;
            float acc = pre[gt];
#pragma unroll 8
            for (int k = 0; k < 256; k++) acc = fmaf(rvb[k], W_memout[k * 512 + c], acc);
            out[(size_t)(T_STEPS - 1) * 8192 + gt] = acc;
        }
    }
}

extern "C" void kernel_launch(void* const* d_in, const int* in_sizes, int n_in,
                              void* d_out, int out_size, void* d_ws, size_t ws_size,
                              hipStream_t stream) {
    (void)in_sizes; (void)n_in; (void)out_size; (void)ws_size;
    const float* x        = (const float*)d_in[0];
    const float* W_hid    = (const float*)d_in[1];
    const float* b_hid    = (const float*)d_in[2];
    const float* W_iface  = (const float*)d_in[3];
    const float* W_out    = (const float*)d_in[4];
    const float* W_memout = (const float*)d_in[5];
    float* outp = (float*)d_out;
    float* ws   = (float*)d_ws;

    void* args[] = {&x, &W_hid, &b_hid, &W_iface, &W_out, &W_memout, &outp, &ws};
    hipLaunchCooperativeKernel((void*)neucom_kernel, dim3(GRID_BLOCKS),
                               dim3(BLOCK_THREADS), args, 0, stream);
}